// Round 5
// baseline (316.769 us; speedup 1.0000x reference)
//
#include <hip/hip_runtime.h>

// Output layout (ALL float32):
//   out[0        .. 8388608)  quantized_st  [4,64,32,32,32]
//   out[8388608  .. 8519680)  embed_idx as float  [4,32,32,32]
//   out[8519680]              latent_loss scalar
#define HWD      32768            // 32*32*32
#define NC       64               // channels / embed dim
#define NE       512              // codebook entries
#define OUT_IDX  8388608
#define OUT_LOSS 8519680

// Constant-address-space views: uniform loads from these lower to s_load_*
// (SMEM pipe, SGPR destination) instead of ds_read/global_load. The inner
// FMA then reads w as its one allowed SGPR operand -> zero LDS traffic.
typedef float vfloat4 __attribute__((ext_vector_type(4)));
typedef const __attribute__((address_space(4))) vfloat4 cvec4;
typedef const __attribute__((address_space(4))) float  cflt;

// ---- prep: codebook row squared-norms into d_ws (512 floats) ----
__global__ __launch_bounds__(256) void vq_norms(
    const float* __restrict__ w, float* __restrict__ wsq)
{
    const int e = blockIdx.x * 256 + threadIdx.x;   // 2 blocks x 256 = 512 rows
    const float4* row = (const float4*)(w + (size_t)e * NC);
    float s0 = 0.f, s1 = 0.f, s2 = 0.f, s3 = 0.f;
#pragma unroll
    for (int k = 0; k < 16; ++k) {
        float4 v = row[k];
        s0 = fmaf(v.x, v.x, s0); s1 = fmaf(v.y, v.y, s1);
        s2 = fmaf(v.z, v.z, s2); s3 = fmaf(v.w, v.w, s3);
    }
    wsq[e] = (s0 + s1) + (s2 + s3);
}

// ---- main: 512 blocks x 256 threads, 1 position/thread, no LDS tiling ----
__global__ __launch_bounds__(256, 2) void vq_main(
    const float* __restrict__ x, const float* __restrict__ w,
    const float* __restrict__ wsq, float* __restrict__ out,
    float* __restrict__ loss_acc)
{
    __shared__ float wred[4];   // loss wave partials only

    const int tid = threadIdx.x;
    const int n   = blockIdx.x * 256 + tid;
    const int b   = n >> 15;
    const int hwd = n & (HWD - 1);
    const float* xp = x + (size_t)b * NC * HWD + hwd;

    // position vector in registers (coalesced: lane <-> hwd)
    float xr[NC];
#pragma unroll
    for (int c = 0; c < NC; ++c) xr[c] = xp[(size_t)c * HWD];
    float xsq = 0.f;
#pragma unroll
    for (int c = 0; c < NC; ++c) xsq = fmaf(xr[c], xr[c], xsq);

    float best = 3.402823466e38f;
    int   bidx = 0;

#pragma unroll 2
    for (int e = 0; e < NE; ++e) {
        // wave-uniform row pointer in constant addrspace -> s_load_dwordx16
        const cvec4* row = (const cvec4*)(unsigned long long)(w + (size_t)e * NC);
        float p0 = 0.f, p1 = 0.f, p2 = 0.f, p3 = 0.f;
#pragma unroll
        for (int k = 0; k < 16; ++k) {
            vfloat4 v = row[k];                 // SGPRs
            p0 = fmaf(xr[4 * k + 0], v.x, p0);  // v_fma_f32 v, s, v, v
            p1 = fmaf(xr[4 * k + 1], v.y, p1);
            p2 = fmaf(xr[4 * k + 2], v.z, p2);
            p3 = fmaf(xr[4 * k + 3], v.w, p3);
        }
        const float dot = (p0 + p1) + (p2 + p3);
        const float we  = *(cflt*)(unsigned long long)(wsq + e);   // s_load_dword
        const float d   = (xsq - 2.f * dot) + we;   // same shape as R3/R4 (passed)
        if (d < best) { best = d; bidx = e; }       // strict <: np first-index
    }

    // ---- epilogue: gather winning row from global (divergent -> VMEM, L2-hot) ----
    const float4* wrow = (const float4*)(w + (size_t)bidx * NC);
    float* o0 = out + (size_t)b * NC * HWD + hwd;
    float lsum = 0.f;
#pragma unroll
    for (int k = 0; k < 16; ++k) {
        float4 q = wrow[k];
        float qv[4] = { q.x, q.y, q.z, q.w };
#pragma unroll
        for (int j = 0; j < 4; ++j) {
            const int c = 4 * k + j;
            const float xv = xr[c];
            const float dq = qv[j] - xv;          // stop_gradient(q - x)
            lsum = fmaf(dq, dq, lsum);
            o0[(size_t)c * HWD] = dq + xv;        // (q-x)+x in fp32, as np
        }
    }
    out[OUT_IDX + n] = (float)bidx;

    // ---- loss: wave shuffle -> block LDS -> one atomic per block ----
#pragma unroll
    for (int off = 32; off >= 1; off >>= 1) lsum += __shfl_down(lsum, off);
    if ((tid & 63) == 0) wred[tid >> 6] = lsum;
    __syncthreads();
    if (tid == 0)
        atomicAdd(loss_acc, (wred[0] + wred[1]) + (wred[2] + wred[3]));
}

__global__ void vq_loss_finalize(const float* __restrict__ loss_acc,
                                 float* __restrict__ out)
{
    out[OUT_LOSS] = 0.25f * loss_acc[0] / 8388608.0f;
}

extern "C" void kernel_launch(void* const* d_in, const int* in_sizes, int n_in,
                              void* d_out, int out_size, void* d_ws, size_t ws_size,
                              hipStream_t stream)
{
    const float* x = (const float*)d_in[0];
    const float* w = (const float*)d_in[1];
    float* out = (float*)d_out;
    float* acc = (float*)d_ws;            // ws[0]: loss accumulator
    float* wsq = (float*)d_ws + 16;       // ws[16..528): row norms (64B aligned)

    hipMemsetAsync(d_ws, 0, sizeof(float), stream);
    vq_norms<<<2, 256, 0, stream>>>(w, wsq);
    vq_main<<<512, 256, 0, stream>>>(x, w, wsq, out, acc);
    vq_loss_finalize<<<1, 1, 0, stream>>>(acc, out);
}

// Round 6
// 206.605 us; speedup vs baseline: 1.5332x; 1.5332x over previous
//
#include <hip/hip_runtime.h>
#include <hip/hip_bf16.h>

// Output layout (ALL float32):
//   out[0        .. 8388608)  quantized_st  [4,64,32,32,32]
//   out[8388608  .. 8519680)  embed_idx as float  [4,32,32,32]
//   out[8519680]              latent_loss scalar
#define HWD      32768
#define NC       64
#define NE       512
#define OUT_IDX  8388608
#define OUT_LOSS 8519680

// ws layout (bytes):
//   [0..4)      loss accumulator (float)
//   [4..8)      completion counter (uint)
//   [64..2112)  wsq[512] (float)
//   [4096..200704) wp: 3-plane bf16 codebook, fragment-swizzled
#define WS_WSQ_F   16          // float offset of wsq
#define WS_WP_B    4096        // byte offset of wp
#define WS_NEEDED  200704

typedef __attribute__((ext_vector_type(8))) short bf16x8;   // 8 bf16 = 4 VGPRs
typedef __attribute__((ext_vector_type(4))) float f32x4;

__device__ inline unsigned short bf16_rne(float v) {
    unsigned u = __builtin_bit_cast(unsigned, v);
    return (unsigned short)((u + 0x7FFFu + ((u >> 16) & 1u)) >> 16);
}
__device__ inline float bf16_f(unsigned short s) {
    return __builtin_bit_cast(float, (unsigned)s << 16);
}
// x = hi + mid + lo EXACTLY (each residual has <=16 / <=8 significant bits)
__device__ inline void split3(float v, unsigned short& h, unsigned short& m,
                              unsigned short& l) {
    h = bf16_rne(v);
    float r1 = v - bf16_f(h);
    m = bf16_rne(r1);
    float r2 = r1 - bf16_f(m);
    l = bf16_rne(r2);
}

// ---------------- prep: zero accumulators, wsq, split+swizzle codebook ----
// grid 48 x 256. wp slot s = ((ct*2+kc)*3+plane)*64 + lane  (16B per slot):
// lane holds w[code=ct*16+(lane&15)][k=kc*32+(lane>>4)*8 + 0..7], one plane.
__global__ __launch_bounds__(256) void vq_prep(
    const float* __restrict__ w, float* __restrict__ ws)
{
    const int gtid = blockIdx.x * 256 + threadIdx.x;   // 0..12287
    if (gtid == 0) { ws[0] = 0.f; ((unsigned*)ws)[1] = 0u; }
    if (gtid < NE) {   // row squared norms (same op order as R3-R5: passed)
        const float4* row = (const float4*)(w + (size_t)gtid * NC);
        float s0 = 0.f, s1 = 0.f, s2 = 0.f, s3 = 0.f;
#pragma unroll
        for (int k = 0; k < 16; ++k) {
            float4 v = row[k];
            s0 = fmaf(v.x, v.x, s0); s1 = fmaf(v.y, v.y, s1);
            s2 = fmaf(v.z, v.z, s2); s3 = fmaf(v.w, v.w, s3);
        }
        ws[WS_WSQ_F + gtid] = (s0 + s1) + (s2 + s3);
    }
    // codebook planes
    const int lane_s = gtid & 63;
    int t = gtid >> 6;            // 0..191
    const int plane = t % 3; t /= 3;
    const int kc = t & 1;
    const int ct = t >> 1;
    const int code = ct * 16 + (lane_s & 15);
    const int kb   = kc * 32 + (lane_s >> 4) * 8;
    const float* src = w + (size_t)code * NC + kb;
    unsigned short o[8];
#pragma unroll
    for (int j = 0; j < 8; ++j) {
        unsigned short h, m, l;
        split3(src[j], h, m, l);
        o[j] = (plane == 0) ? h : (plane == 1) ? m : l;
    }
    unsigned short* dst = (unsigned short*)((char*)ws + WS_WP_B) + (size_t)gtid * 8;
#pragma unroll
    for (int j = 0; j < 8; ++j) dst[j] = o[j];
}

// ---------------- main: MFMA distance GEMM + argmin + fused epilogue ------
// 512 blocks x 256 threads (4 waves); wave gw owns 64 consecutive positions.
__global__ __launch_bounds__(256, 2) void vq_mfma(
    const float* __restrict__ x, const float* __restrict__ w,
    float* __restrict__ ws, float* __restrict__ out)
{
    __shared__ int   idx_sh[4][64];
    __shared__ float xsq_sh[4][64];
    __shared__ float wred[4];

    const int tid    = threadIdx.x;
    const int wv     = tid >> 6;
    const int lane   = tid & 63;
    const int lanelo = lane & 15;
    const int quad   = lane >> 4;
    const int gw     = blockIdx.x * 4 + wv;      // 0..2047
    const int pos_b  = gw * 64;
    const int b      = pos_b >> 15;
    const int hwd_b  = pos_b & (HWD - 1);
    const size_t xoff = (size_t)b * NC * HWD + hwd_b;

    // ---- phase 1: x -> A-fragments (3 bf16 planes), plus xsq ----
    // A-layout (m89/m120-verified): lane holds A[m=lane&15][k=quad*8+j]
    bf16x8 A[4][2][3];
    float  xsqp[4] = {0.f, 0.f, 0.f, 0.f};
#pragma unroll
    for (int pt = 0; pt < 4; ++pt) {
#pragma unroll
        for (int kc = 0; kc < 2; ++kc) {
            bf16x8 fh, fm, fl;
            float xs = 0.f;
#pragma unroll
            for (int j = 0; j < 8; ++j) {
                const int k = kc * 32 + quad * 8 + j;
                const float v = x[xoff + (size_t)k * HWD + pt * 16 + lanelo];
                unsigned short h, m, l;
                split3(v, h, m, l);
                fh[j] = (short)h; fm[j] = (short)m; fl[j] = (short)l;
                xs = fmaf(v, v, xs);
            }
            A[pt][kc][0] = fh; A[pt][kc][1] = fm; A[pt][kc][2] = fl;
            xsqp[pt] += xs;
        }
        // complete xsq across quads (k was split 16-per-quad-pair)
        xsqp[pt] += __shfl_xor(xsqp[pt], 16);
        xsqp[pt] += __shfl_xor(xsqp[pt], 32);
        if (quad == 0) xsq_sh[wv][pt * 16 + lanelo] = xsqp[pt];
    }
    __syncthreads();

    // xsq for this lane's C-rows (row = quad*4 + reg), ct-invariant
    float xsq_r[4][4];
#pragma unroll
    for (int pt = 0; pt < 4; ++pt)
#pragma unroll
        for (int r = 0; r < 4; ++r)
            xsq_r[pt][r] = xsq_sh[wv][pt * 16 + quad * 4 + r];

    const bf16x8* wp = (const bf16x8*)((const char*)ws + WS_WP_B);
    const float*  wsqp = ws + WS_WSQ_F;

    float best[4][4];
    int   bidx[4][4];
#pragma unroll
    for (int pt = 0; pt < 4; ++pt)
#pragma unroll
        for (int r = 0; r < 4; ++r) { best[pt][r] = 3.402823466e38f; bidx[pt][r] = 0; }

    // ---- phase 2: 32 code-tiles; 12 chained MFMAs per (pt, tile) ----
    for (int ct = 0; ct < 32; ++ct) {
        bf16x8 B[2][3];
#pragma unroll
        for (int kc = 0; kc < 2; ++kc)
#pragma unroll
            for (int p = 0; p < 3; ++p)
                B[kc][p] = wp[(size_t)((ct * 2 + kc) * 3 + p) * 64 + lane];
        const float wsq_c = wsqp[ct * 16 + lanelo];   // col = lane&15

#pragma unroll
        for (int pt = 0; pt < 4; ++pt) {
            f32x4 acc = {0.f, 0.f, 0.f, 0.f};
            // smallest terms first: x3w1, x2w2, x1w3 (~2^-16) then 2^-8 then 1
            acc = __builtin_amdgcn_mfma_f32_16x16x32_bf16(A[pt][0][2], B[0][0], acc, 0, 0, 0);
            acc = __builtin_amdgcn_mfma_f32_16x16x32_bf16(A[pt][1][2], B[1][0], acc, 0, 0, 0);
            acc = __builtin_amdgcn_mfma_f32_16x16x32_bf16(A[pt][0][1], B[0][1], acc, 0, 0, 0);
            acc = __builtin_amdgcn_mfma_f32_16x16x32_bf16(A[pt][1][1], B[1][1], acc, 0, 0, 0);
            acc = __builtin_amdgcn_mfma_f32_16x16x32_bf16(A[pt][0][0], B[0][2], acc, 0, 0, 0);
            acc = __builtin_amdgcn_mfma_f32_16x16x32_bf16(A[pt][1][0], B[1][2], acc, 0, 0, 0);
            acc = __builtin_amdgcn_mfma_f32_16x16x32_bf16(A[pt][0][1], B[0][0], acc, 0, 0, 0);
            acc = __builtin_amdgcn_mfma_f32_16x16x32_bf16(A[pt][1][1], B[1][0], acc, 0, 0, 0);
            acc = __builtin_amdgcn_mfma_f32_16x16x32_bf16(A[pt][0][0], B[0][1], acc, 0, 0, 0);
            acc = __builtin_amdgcn_mfma_f32_16x16x32_bf16(A[pt][1][0], B[1][1], acc, 0, 0, 0);
            acc = __builtin_amdgcn_mfma_f32_16x16x32_bf16(A[pt][0][0], B[0][0], acc, 0, 0, 0);
            acc = __builtin_amdgcn_mfma_f32_16x16x32_bf16(A[pt][1][0], B[1][0], acc, 0, 0, 0);
            // C layout: col(code)=lane&15, row(pos)=quad*4+r  [m89/m91]
#pragma unroll
            for (int r = 0; r < 4; ++r) {
                const float d = fmaf(-2.f, acc[r], xsq_r[pt][r]) + wsq_c;
                const int ge = ct * 16 + lanelo;
                if (d < best[pt][r]) { best[pt][r] = d; bidx[pt][r] = ge; }
            }
        }
    }

    // ---- phase 3: argmin across the 16 code-columns (np first-index ties) ----
#pragma unroll
    for (int pt = 0; pt < 4; ++pt)
#pragma unroll
        for (int r = 0; r < 4; ++r) {
            float d = best[pt][r]; int i = bidx[pt][r];
#pragma unroll
            for (int mlane = 1; mlane <= 8; mlane <<= 1) {
                const float d2 = __shfl_xor(d, mlane);
                const int   i2 = __shfl_xor(i, mlane);
                if (d2 < d || (d2 == d && i2 < i)) { d = d2; i = i2; }
            }
            if (lanelo == 0) {
                idx_sh[wv][pt * 16 + quad * 4 + r] = i;
                out[OUT_IDX + pos_b + pt * 16 + quad * 4 + r] = (float)i;
            }
        }
    __syncthreads();

    // ---- phase 4: gather + straight-through write + loss ----
    int myidx[4];
#pragma unroll
    for (int pt = 0; pt < 4; ++pt) myidx[pt] = idx_sh[wv][pt * 16 + lanelo];

    float lsum = 0.f;
#pragma unroll
    for (int pt = 0; pt < 4; ++pt)
#pragma unroll
        for (int kc = 0; kc < 2; ++kc)
#pragma unroll
            for (int j = 0; j < 8; ++j) {
                const int k = kc * 32 + quad * 8 + j;
                const float q  = w[(size_t)myidx[pt] * NC + k];   // L1/L2-hot
                const float xv = bf16_f((unsigned short)A[pt][kc][0][j])
                               + bf16_f((unsigned short)A[pt][kc][1][j])
                               + bf16_f((unsigned short)A[pt][kc][2][j]); // exact x
                const float dq = q - xv;
                lsum = fmaf(dq, dq, lsum);
                out[xoff + (size_t)k * HWD + pt * 16 + lanelo] = dq + xv;
            }

#pragma unroll
    for (int off = 32; off >= 1; off >>= 1) lsum += __shfl_down(lsum, off);
    if (lane == 0) wred[wv] = lsum;
    __syncthreads();
    if (tid == 0) {
        atomicAdd((float*)ws, (wred[0] + wred[1]) + (wred[2] + wred[3]));
        __threadfence();
        const unsigned done = atomicAdd((unsigned*)ws + 1, 1u);
        if (done == 511u) {
            const float L = atomicAdd((float*)ws, 0.f);   // device-scope read
            out[OUT_LOSS] = 0.25f * L / 8388608.0f;
        }
    }
}

// ---------------- fallback (R4, known-passing 203us) if ws too small ------
__global__ __launch_bounds__(256, 2) void vq_fused_fb(
    const float* __restrict__ x, const float* __restrict__ w,
    float* __restrict__ out, float* __restrict__ loss_acc)
{
    __shared__ float lw[256 * NC];
    __shared__ float wsq[256];
    __shared__ float wred[4];
    const int tid = threadIdx.x;
    const int n0  = blockIdx.x * 512;
    const int b   = n0 >> 15;
    const int hwd = (n0 & (HWD - 1)) + tid;
    const float* xp = x + (size_t)b * NC * HWD + hwd;
    float xr0[NC], xr1[NC];
#pragma unroll
    for (int c = 0; c < NC; ++c) { xr0[c] = xp[(size_t)c * HWD]; xr1[c] = xp[(size_t)c * HWD + 256]; }
    float xsq0 = 0.f, xsq1 = 0.f;
#pragma unroll
    for (int c = 0; c < NC; ++c) { xsq0 = fmaf(xr0[c], xr0[c], xsq0); xsq1 = fmaf(xr1[c], xr1[c], xsq1); }
    float best0 = 3.402823466e38f, best1 = 3.402823466e38f;
    int bi0 = 0, bi1 = 0;
    for (int pass = 0; pass < 2; ++pass) {
        if (pass) __syncthreads();
        const float4* wt = (const float4*)(w + pass * 256 * NC);
        float4* l4 = (float4*)lw;
#pragma unroll
        for (int k = 0; k < 16; ++k) l4[tid + k * 256] = wt[tid + k * 256];
        {
            const float4* row = wt + tid * 16;
            float s0 = 0.f, s1 = 0.f, s2 = 0.f, s3 = 0.f;
#pragma unroll
            for (int k = 0; k < 16; ++k) {
                float4 v = row[k];
                s0 = fmaf(v.x, v.x, s0); s1 = fmaf(v.y, v.y, s1);
                s2 = fmaf(v.z, v.z, s2); s3 = fmaf(v.w, v.w, s3);
            }
            wsq[tid] = (s0 + s1) + (s2 + s3);
        }
        __syncthreads();
#pragma unroll 2
        for (int e = 0; e < 256; ++e) {
            const float4* row = (const float4*)(lw + e * NC);
            float a0 = 0.f, a1 = 0.f, c0 = 0.f, c1 = 0.f;
#pragma unroll
            for (int k = 0; k < 16; ++k) {
                float4 v = row[k];
                a0 = fmaf(xr0[4 * k + 0], v.x, a0); a1 = fmaf(xr0[4 * k + 1], v.y, a1);
                a0 = fmaf(xr0[4 * k + 2], v.z, a0); a1 = fmaf(xr0[4 * k + 3], v.w, a1);
                c0 = fmaf(xr1[4 * k + 0], v.x, c0); c1 = fmaf(xr1[4 * k + 1], v.y, c1);
                c0 = fmaf(xr1[4 * k + 2], v.z, c0); c1 = fmaf(xr1[4 * k + 3], v.w, c1);
            }
            const float d0 = (xsq0 - 2.f * (a0 + a1)) + wsq[e];
            const float d1 = (xsq1 - 2.f * (c0 + c1)) + wsq[e];
            const int ge = pass * 256 + e;
            if (d0 < best0) { best0 = d0; bi0 = ge; }
            if (d1 < best1) { best1 = d1; bi1 = ge; }
        }
    }
    float* o0 = out + (size_t)b * NC * HWD + hwd;
    float lsum = 0.f;
    const float4* r0 = (const float4*)(w + bi0 * NC);
    const float4* r1 = (const float4*)(w + bi1 * NC);
#pragma unroll
    for (int k = 0; k < 16; ++k) {
        float4 q0 = r0[k], q1 = r1[k];
        float qv0[4] = { q0.x, q0.y, q0.z, q0.w };
        float qv1[4] = { q1.x, q1.y, q1.z, q1.w };
#pragma unroll
        for (int j = 0; j < 4; ++j) {
            const int c = 4 * k + j;
            const float dv0 = qv0[j] - xr0[c];
            const float dv1 = qv1[j] - xr1[c];
            lsum = fmaf(dv0, dv0, lsum); lsum = fmaf(dv1, dv1, lsum);
            o0[(size_t)c * HWD] = dv0 + xr0[c];
            o0[(size_t)c * HWD + 256] = dv1 + xr1[c];
        }
    }
    const int n = b * HWD + hwd;
    out[OUT_IDX + n] = (float)bi0;
    out[OUT_IDX + n + 256] = (float)bi1;
#pragma unroll
    for (int off = 32; off >= 1; off >>= 1) lsum += __shfl_down(lsum, off);
    if ((tid & 63) == 0) wred[tid >> 6] = lsum;
    __syncthreads();
    if (tid == 0) atomicAdd(loss_acc, (wred[0] + wred[1]) + (wred[2] + wred[3]));
}

__global__ void vq_loss_fin_fb(const float* __restrict__ acc, float* __restrict__ out)
{
    out[OUT_LOSS] = 0.25f * acc[0] / 8388608.0f;
}

extern "C" void kernel_launch(void* const* d_in, const int* in_sizes, int n_in,
                              void* d_out, int out_size, void* d_ws, size_t ws_size,
                              hipStream_t stream)
{
    const float* x = (const float*)d_in[0];
    const float* w = (const float*)d_in[1];
    float* out = (float*)d_out;
    float* ws  = (float*)d_ws;

    if (ws_size >= WS_NEEDED) {
        vq_prep<<<48, 256, 0, stream>>>(w, ws);
        vq_mfma<<<512, 256, 0, stream>>>(x, w, ws, out);
    } else {   // fallback: known-passing LDS path
        hipMemsetAsync(d_ws, 0, sizeof(float), stream);
        vq_fused_fb<<<256, 256, 0, stream>>>(x, w, out, ws);
        vq_loss_fin_fb<<<1, 1, 0, stream>>>(ws, out);
    }
}

// Round 7
// 166.961 us; speedup vs baseline: 1.8973x; 1.2374x over previous
//
#include <hip/hip_runtime.h>
#include <hip/hip_bf16.h>

// Output layout (ALL float32):
//   out[0        .. 8388608)  quantized_st  [4,64,32,32,32]
//   out[8388608  .. 8519680)  embed_idx as float  [4,32,32,32]
//   out[8519680]              latent_loss scalar
#define HWD      32768
#define NC       64
#define NE       512
#define OUT_IDX  8388608
#define OUT_LOSS 8519680

// ws layout (bytes):
//   [0..4)   loss accumulator   [4..8) completion counter
//   [64..2112) wsq[512]         [4096..200704) wp 3-plane bf16 codebook
#define WS_WSQ_F   16
#define WS_WP_B    4096
#define WS_NEEDED  200704

typedef __attribute__((ext_vector_type(8))) short bf16x8;
typedef __attribute__((ext_vector_type(4))) float f32x4;

__device__ inline unsigned short bf16_rne(float v) {
    unsigned u = __builtin_bit_cast(unsigned, v);
    return (unsigned short)((u + 0x7FFFu + ((u >> 16) & 1u)) >> 16);
}
__device__ inline float bf16_f(unsigned short s) {
    return __builtin_bit_cast(float, (unsigned)s << 16);
}
__device__ inline void split3(float v, unsigned short& h, unsigned short& m,
                              unsigned short& l) {
    h = bf16_rne(v);
    float r1 = v - bf16_f(h);
    m = bf16_rne(r1);
    float r2 = r1 - bf16_f(m);
    l = bf16_rne(r2);
}

// ---------------- prep: zero accumulators, wsq, split+swizzle codebook ----
// (unchanged from R6 — verified)
__global__ __launch_bounds__(256) void vq_prep(
    const float* __restrict__ w, float* __restrict__ ws)
{
    const int gtid = blockIdx.x * 256 + threadIdx.x;   // 0..12287
    if (gtid == 0) { ws[0] = 0.f; ((unsigned*)ws)[1] = 0u; }
    if (gtid < NE) {
        const float4* row = (const float4*)(w + (size_t)gtid * NC);
        float s0 = 0.f, s1 = 0.f, s2 = 0.f, s3 = 0.f;
#pragma unroll
        for (int k = 0; k < 16; ++k) {
            float4 v = row[k];
            s0 = fmaf(v.x, v.x, s0); s1 = fmaf(v.y, v.y, s1);
            s2 = fmaf(v.z, v.z, s2); s3 = fmaf(v.w, v.w, s3);
        }
        ws[WS_WSQ_F + gtid] = (s0 + s1) + (s2 + s3);
    }
    const int lane_s = gtid & 63;
    int t = gtid >> 6;            // 0..191
    const int plane = t % 3; t /= 3;
    const int kc = t & 1;
    const int ct = t >> 1;
    const int code = ct * 16 + (lane_s & 15);
    const int kb   = kc * 32 + (lane_s >> 4) * 8;
    const float* src = w + (size_t)code * NC + kb;
    unsigned short o[8];
#pragma unroll
    for (int j = 0; j < 8; ++j) {
        unsigned short h, m, l;
        split3(src[j], h, m, l);
        o[j] = (plane == 0) ? h : (plane == 1) ? m : l;
    }
    unsigned short* dst = (unsigned short*)((char*)ws + WS_WP_B) + (size_t)gtid * 8;
#pragma unroll
    for (int j = 0; j < 8; ++j) dst[j] = o[j];
}

// ---------------- fused main: 1024 blocks x 256 thr, 128 pos/block --------
// Each wave owns 32 positions (2 MFMA row-tiles) -> 4096 waves, 16 waves/CU.
__global__ __launch_bounds__(256, 4) void vq_fused2(
    const float* __restrict__ x, const float* __restrict__ w,
    float* __restrict__ ws, float* __restrict__ out)
{
    __shared__ float q_sh[128 * 65];   // selected rows, padded (33.3 KB)
    __shared__ int   idx_sh[128];
    __shared__ float wred[4];

    const int tid    = threadIdx.x;
    const int wv     = tid >> 6;
    const int lane   = tid & 63;
    const int lanelo = lane & 15;
    const int quad   = lane >> 4;
    const int posB   = blockIdx.x * 128;
    const int b      = posB >> 15;
    const int hwdB   = posB & (HWD - 1);
    const size_t xoff = (size_t)b * NC * HWD + hwdB;
    const int wpos   = wv * 32;        // wave's first position within block

    // ---- phase 1: A-fragments (3 exact bf16 planes) + xsq ----
    bf16x8 A[2][2][3];
    float  xsqp[2];
#pragma unroll
    for (int pt = 0; pt < 2; ++pt) {
        float xs = 0.f;
#pragma unroll
        for (int kc = 0; kc < 2; ++kc) {
            bf16x8 fh, fm, fl;
#pragma unroll
            for (int j = 0; j < 8; ++j) {
                const int k = kc * 32 + quad * 8 + j;
                const float v = x[xoff + (size_t)k * HWD + wpos + pt * 16 + lanelo];
                unsigned short h, m, l;
                split3(v, h, m, l);
                fh[j] = (short)h; fm[j] = (short)m; fl[j] = (short)l;
                xs = fmaf(v, v, xs);
            }
            A[pt][kc][0] = fh; A[pt][kc][1] = fm; A[pt][kc][2] = fl;
        }
        xs += __shfl_xor(xs, 16);
        xs += __shfl_xor(xs, 32);      // full 64-ch norm, replicated over quads
        xsqp[pt] = xs;
    }
    // xsq for this lane's C-rows (row = quad*4+r) via shuffle
    float xsq_r[2][4];
#pragma unroll
    for (int pt = 0; pt < 2; ++pt)
#pragma unroll
        for (int r = 0; r < 4; ++r)
            xsq_r[pt][r] = __shfl(xsqp[pt], quad * 4 + r);

    const bf16x8* wp   = (const bf16x8*)((const char*)ws + WS_WP_B);
    const float*  wsqp = ws + WS_WSQ_F;

    float best[2][4];
    int   bidx[2][4];
#pragma unroll
    for (int pt = 0; pt < 2; ++pt)
#pragma unroll
        for (int r = 0; r < 4; ++r) { best[pt][r] = 3.402823466e38f; bidx[pt][r] = 0; }

    // ---- phase 2: 32 code-tiles, 12 chained MFMAs per (pt,tile) ----
    for (int ct = 0; ct < 32; ++ct) {
        bf16x8 B[2][3];
#pragma unroll
        for (int kc = 0; kc < 2; ++kc)
#pragma unroll
            for (int p = 0; p < 3; ++p)
                B[kc][p] = wp[(size_t)((ct * 2 + kc) * 3 + p) * 64 + lane];
        const float wsq_c = wsqp[ct * 16 + lanelo];

#pragma unroll
        for (int pt = 0; pt < 2; ++pt) {
            f32x4 acc = {0.f, 0.f, 0.f, 0.f};
            acc = __builtin_amdgcn_mfma_f32_16x16x32_bf16(A[pt][0][2], B[0][0], acc, 0, 0, 0);
            acc = __builtin_amdgcn_mfma_f32_16x16x32_bf16(A[pt][1][2], B[1][0], acc, 0, 0, 0);
            acc = __builtin_amdgcn_mfma_f32_16x16x32_bf16(A[pt][0][1], B[0][1], acc, 0, 0, 0);
            acc = __builtin_amdgcn_mfma_f32_16x16x32_bf16(A[pt][1][1], B[1][1], acc, 0, 0, 0);
            acc = __builtin_amdgcn_mfma_f32_16x16x32_bf16(A[pt][0][0], B[0][2], acc, 0, 0, 0);
            acc = __builtin_amdgcn_mfma_f32_16x16x32_bf16(A[pt][1][0], B[1][2], acc, 0, 0, 0);
            acc = __builtin_amdgcn_mfma_f32_16x16x32_bf16(A[pt][0][1], B[0][0], acc, 0, 0, 0);
            acc = __builtin_amdgcn_mfma_f32_16x16x32_bf16(A[pt][1][1], B[1][0], acc, 0, 0, 0);
            acc = __builtin_amdgcn_mfma_f32_16x16x32_bf16(A[pt][0][0], B[0][1], acc, 0, 0, 0);
            acc = __builtin_amdgcn_mfma_f32_16x16x32_bf16(A[pt][1][0], B[1][1], acc, 0, 0, 0);
            acc = __builtin_amdgcn_mfma_f32_16x16x32_bf16(A[pt][0][0], B[0][0], acc, 0, 0, 0);
            acc = __builtin_amdgcn_mfma_f32_16x16x32_bf16(A[pt][1][0], B[1][0], acc, 0, 0, 0);
#pragma unroll
            for (int r = 0; r < 4; ++r) {
                const float d = fmaf(-2.f, acc[r], xsq_r[pt][r]) + wsq_c;
                const int ge = ct * 16 + lanelo;
                if (d < best[pt][r]) { best[pt][r] = d; bidx[pt][r] = ge; }
            }
        }
    }

    // ---- phase 3: argmin across 16 code-columns (np first-index ties) ----
#pragma unroll
    for (int pt = 0; pt < 2; ++pt)
#pragma unroll
        for (int r = 0; r < 4; ++r) {
            float d = best[pt][r]; int i = bidx[pt][r];
#pragma unroll
            for (int mlane = 1; mlane <= 8; mlane <<= 1) {
                const float d2 = __shfl_xor(d, mlane);
                const int   i2 = __shfl_xor(i, mlane);
                if (d2 < d || (d2 == d && i2 < i)) { d = d2; i = i2; }
            }
            if (lanelo == 0)
                idx_sh[wpos + pt * 16 + quad * 4 + r] = i;
        }
    __syncthreads();

    // idx output: one coalesced 128-float run per block
    if (tid < 128) out[OUT_IDX + posB + tid] = (float)idx_sh[tid];

    // ---- phase 4a: stage the 128 selected rows into LDS (coalesced w reads,
    //      pad-65 makes both the write and the strided read conflict-free) ----
#pragma unroll
    for (int it = 0; it < 32; ++it) {
        const int e = it * 256 + tid;       // 0..8191
        const int r = e >> 6, c = e & 63;   // per 64-lane group: r fixed, c=0..63
        q_sh[r * 65 + c] = w[(size_t)idx_sh[r] * NC + c];
    }
    __syncthreads();

    // ---- phase 4b: channel-major epilogue, fully coalesced x/out ----
    float lsum = 0.f;
#pragma unroll
    for (int it = 0; it < 32; ++it) {
        const int e = it * 256 + tid;
        const int c = e >> 7;               // per 64-lane group: c fixed
        const int p = e & 127;              // p consecutive
        const size_t off = xoff + (size_t)c * HWD + p;
        const float xv = x[off];
        const float q  = q_sh[p * 65 + c];  // banks (p+c)%32: conflict-free
        const float dq = q - xv;
        lsum = fmaf(dq, dq, lsum);
        out[off] = dq + xv;                 // (q-x)+x in fp32, as np
    }

    // ---- loss: wave shuffle -> block LDS -> atomic; last block finalizes ----
#pragma unroll
    for (int off = 32; off >= 1; off >>= 1) lsum += __shfl_down(lsum, off);
    if (lane == 0) wred[wv] = lsum;
    __syncthreads();
    if (tid == 0) {
        atomicAdd((float*)ws, (wred[0] + wred[1]) + (wred[2] + wred[3]));
        __threadfence();
        const unsigned done = atomicAdd((unsigned*)ws + 1, 1u);
        if (done == 1023u) {
            const float L = atomicAdd((float*)ws, 0.f);
            out[OUT_LOSS] = 0.25f * L / 8388608.0f;
        }
    }
}

// ---------------- fallback (R4 structure, known-passing) ------------------
__global__ __launch_bounds__(256, 2) void vq_fused_fb(
    const float* __restrict__ x, const float* __restrict__ w,
    float* __restrict__ out, float* __restrict__ loss_acc)
{
    __shared__ float lw[256 * NC];
    __shared__ float wsq[256];
    __shared__ float wred[4];
    const int tid = threadIdx.x;
    const int n0  = blockIdx.x * 512;
    const int b   = n0 >> 15;
    const int hwd = (n0 & (HWD - 1)) + tid;
    const float* xp = x + (size_t)b * NC * HWD + hwd;
    float xr0[NC], xr1[NC];
#pragma unroll
    for (int c = 0; c < NC; ++c) { xr0[c] = xp[(size_t)c * HWD]; xr1[c] = xp[(size_t)c * HWD + 256]; }
    float xsq0 = 0.f, xsq1 = 0.f;
#pragma unroll
    for (int c = 0; c < NC; ++c) { xsq0 = fmaf(xr0[c], xr0[c], xsq0); xsq1 = fmaf(xr1[c], xr1[c], xsq1); }
    float best0 = 3.402823466e38f, best1 = 3.402823466e38f;
    int bi0 = 0, bi1 = 0;
    for (int pass = 0; pass < 2; ++pass) {
        if (pass) __syncthreads();
        const float4* wt = (const float4*)(w + pass * 256 * NC);
        float4* l4 = (float4*)lw;
#pragma unroll
        for (int k = 0; k < 16; ++k) l4[tid + k * 256] = wt[tid + k * 256];
        {
            const float4* row = wt + tid * 16;
            float s0 = 0.f, s1 = 0.f, s2 = 0.f, s3 = 0.f;
#pragma unroll
            for (int k = 0; k < 16; ++k) {
                float4 v = row[k];
                s0 = fmaf(v.x, v.x, s0); s1 = fmaf(v.y, v.y, s1);
                s2 = fmaf(v.z, v.z, s2); s3 = fmaf(v.w, v.w, s3);
            }
            wsq[tid] = (s0 + s1) + (s2 + s3);
        }
        __syncthreads();
#pragma unroll 2
        for (int e = 0; e < 256; ++e) {
            const float4* row = (const float4*)(lw + e * NC);
            float a0 = 0.f, a1 = 0.f, c0 = 0.f, c1 = 0.f;
#pragma unroll
            for (int k = 0; k < 16; ++k) {
                float4 v = row[k];
                a0 = fmaf(xr0[4 * k + 0], v.x, a0); a1 = fmaf(xr0[4 * k + 1], v.y, a1);
                a0 = fmaf(xr0[4 * k + 2], v.z, a0); a1 = fmaf(xr0[4 * k + 3], v.w, a1);
                c0 = fmaf(xr1[4 * k + 0], v.x, c0); c1 = fmaf(xr1[4 * k + 1], v.y, c1);
                c0 = fmaf(xr1[4 * k + 2], v.z, c0); c1 = fmaf(xr1[4 * k + 3], v.w, c1);
            }
            const float d0 = (xsq0 - 2.f * (a0 + a1)) + wsq[e];
            const float d1 = (xsq1 - 2.f * (c0 + c1)) + wsq[e];
            const int ge = pass * 256 + e;
            if (d0 < best0) { best0 = d0; bi0 = ge; }
            if (d1 < best1) { best1 = d1; bi1 = ge; }
        }
    }
    float* o0 = out + (size_t)b * NC * HWD + hwd;
    float lsum = 0.f;
    const float4* r0 = (const float4*)(w + bi0 * NC);
    const float4* r1 = (const float4*)(w + bi1 * NC);
#pragma unroll
    for (int k = 0; k < 16; ++k) {
        float4 q0 = r0[k], q1 = r1[k];
        float qv0[4] = { q0.x, q0.y, q0.z, q0.w };
        float qv1[4] = { q1.x, q1.y, q1.z, q1.w };
#pragma unroll
        for (int j = 0; j < 4; ++j) {
            const int c = 4 * k + j;
            const float dv0 = qv0[j] - xr0[c];
            const float dv1 = qv1[j] - xr1[c];
            lsum = fmaf(dv0, dv0, lsum); lsum = fmaf(dv1, dv1, lsum);
            o0[(size_t)c * HWD] = dv0 + xr0[c];
            o0[(size_t)c * HWD + 256] = dv1 + xr1[c];
        }
    }
    const int n = b * HWD + hwd;
    out[OUT_IDX + n] = (float)bi0;
    out[OUT_IDX + n + 256] = (float)bi1;
#pragma unroll
    for (int off = 32; off >= 1; off >>= 1) lsum += __shfl_down(lsum, off);
    if ((tid & 63) == 0) wred[tid >> 6] = lsum;
    __syncthreads();
    if (tid == 0) atomicAdd(loss_acc, (wred[0] + wred[1]) + (wred[2] + wred[3]));
}

__global__ void vq_loss_fin_fb(const float* __restrict__ acc, float* __restrict__ out)
{
    out[OUT_LOSS] = 0.25f * acc[0] / 8388608.0f;
}

extern "C" void kernel_launch(void* const* d_in, const int* in_sizes, int n_in,
                              void* d_out, int out_size, void* d_ws, size_t ws_size,
                              hipStream_t stream)
{
    const float* x = (const float*)d_in[0];
    const float* w = (const float*)d_in[1];
    float* out = (float*)d_out;
    float* ws  = (float*)d_ws;

    if (ws_size >= WS_NEEDED) {
        vq_prep<<<48, 256, 0, stream>>>(w, ws);
        vq_fused2<<<1024, 256, 0, stream>>>(x, w, ws, out);
    } else {
        hipMemsetAsync(d_ws, 0, sizeof(float), stream);
        vq_fused_fb<<<256, 256, 0, stream>>>(x, w, out, ws);
        vq_loss_fin_fb<<<1, 1, 0, stream>>>(ws, out);
    }
}